// Round 13
// baseline (284.347 us; speedup 1.0000x reference)
//
#include <hip/hip_runtime.h>
#include <math.h>

constexpr int B = 4, L = 2048, S = 2048, H = 8, D = 64;
constexpr int U  = 40;
constexpr int NT = 40;
constexpr float SCALE = 0.125f;

// ---------------------------------------------------------------- K1: M scores + v-mean partials
// M part: 2 waves per l (u split 20/20) -> half the serial gather chain.
// Lane = h*8+dg as in R11 (proven, no scratch). LDS combine of (vmax,vsum).
__global__ void k_M_meanvpart(const float* __restrict__ q, const float* __restrict__ k,
                              const float* __restrict__ v, const int* __restrict__ idx,
                              float* __restrict__ M, float* __restrict__ part) {
    int tid = threadIdx.x;
    if (blockIdx.x < 4096) {
        int wid = tid >> 6, lane = tid & 63;
        int b = blockIdx.x & 3;
        int lp = wid >> 1, uh = wid & 1;          // local l, u-half
        int l = (blockIdx.x >> 2) * 2 + lp;
        int h = lane >> 3, dg = lane & 7;

        const float4* qr = (const float4*)(q + ((size_t)(b * L + l) * H + h) * D + dg * 8);
        float4 q0 = qr[0], q1 = qr[1];

        const int* irow = idx + l * U + uh * 20;
        const float* kb = k + (size_t)b * S * H * D + (size_t)h * D + dg * 8;
        float vmax = -INFINITY, vsum = 0.f;
#pragma unroll 4
        for (int u = 0; u < 20; u++) {
            int s = irow[u];
            const float4* kr = (const float4*)(kb + (size_t)s * H * D);
            float4 k0 = kr[0], k1 = kr[1];
            float acc = q0.x * k0.x + q0.y * k0.y + q0.z * k0.z + q0.w * k0.w
                      + q1.x * k1.x + q1.y * k1.y + q1.z * k1.z + q1.w * k1.w;
            acc += __shfl_xor(acc, 1);
            acc += __shfl_xor(acc, 2);
            acc += __shfl_xor(acc, 4);
            vmax = fmaxf(vmax, acc);
            vsum += acc;
        }
        __shared__ float2 comb[4][8];
        if (dg == 0) comb[wid][h] = make_float2(vmax, vsum);
        __syncthreads();
        if (tid < 16) {
            int lp2 = tid >> 3, h2 = tid & 7;
            float2 c0 = comb[lp2 * 2][h2], c1 = comb[lp2 * 2 + 1][h2];
            float mx = fmaxf(c0.x, c1.x);
            float sm = c0.y + c1.y;
            int l2 = (blockIdx.x >> 2) * 2 + lp2;
            M[(size_t)(b * H + h2) * L + l2] = mx - sm / (float)S;
        }
    } else {
        int blk = blockIdx.x - 4096;         // 0..127 = b*32 + c
        int b = blk >> 5, c = blk & 31;
        const float* p = v + ((size_t)(b * S + c * 64)) * 512;
        float a0 = 0.f, a1 = 0.f;
#pragma unroll
        for (int s = 0; s < 64; s++) {
            a0 += p[(size_t)s * 512 + tid];
            a1 += p[(size_t)s * 512 + tid + 256];
        }
        part[(size_t)blk * 512 + tid]       = a0;
        part[(size_t)blk * 512 + tid + 256] = a1;
    }
}

// ---------------------------------------------------------------- K2: top-40 radix select (+bitmap) + v-mean final
__device__ inline unsigned int fkey(float f) {
    unsigned int u = __float_as_uint(f);
    return (u & 0x80000000u) ? ~u : (u | 0x80000000u);
}

__global__ void k_topk_meanv(const float* __restrict__ M, int* __restrict__ topidx,
                             const float* __restrict__ part, float* __restrict__ meanv,
                             unsigned int* __restrict__ bitmap) {
    int tid = threadIdx.x;
    if (blockIdx.x >= 32) {
        int b = blockIdx.x - 32;             // 0..3
        float a0 = 0.f, a1 = 0.f;
#pragma unroll
        for (int c = 0; c < 32; c++) {
            a0 += part[(size_t)(b * 32 + c) * 512 + tid];
            a1 += part[(size_t)(b * 32 + c) * 512 + tid + 256];
        }
        meanv[b * 512 + tid]       = a0 * (1.f / (float)S);
        meanv[b * 512 + tid + 256] = a1 * (1.f / (float)S);
        return;
    }
    int bh = blockIdx.x;
    const float* m = M + (size_t)bh * L;

    __shared__ int hist[256];
    __shared__ unsigned int prefix_s;
    __shared__ int c_above_s, nsel_s, ntie_s, r_s;
    __shared__ int tie_i[L];
    __shared__ unsigned int bw[64];

    if (tid < 64) bw[tid] = 0u;

    unsigned int o[8];
    const float4* mr = (const float4*)(m + tid * 8);
    float4 a0 = mr[0], a1 = mr[1];
    o[0] = fkey(a0.x); o[1] = fkey(a0.y); o[2] = fkey(a0.z); o[3] = fkey(a0.w);
    o[4] = fkey(a1.x); o[5] = fkey(a1.y); o[6] = fkey(a1.z); o[7] = fkey(a1.w);

    if (tid == 0) { prefix_s = 0u; c_above_s = 0; nsel_s = 0; ntie_s = 0; }

    for (int sh = 24; sh >= 0; sh -= 8) {
        hist[tid] = 0;
        __syncthreads();
        unsigned int pfx = prefix_s;
#pragma unroll
        for (int j = 0; j < 8; j++) {
            bool match = (sh == 24) || ((o[j] >> (sh + 8)) == (pfx >> (sh + 8)));
            if (match) atomicAdd(&hist[(o[j] >> sh) & 0xFF], 1);
        }
        __syncthreads();
        if (tid < 64) {
            int4 hv = *(const int4*)&hist[tid * 4];
            int lsum = hv.x + hv.y + hv.z + hv.w;
            int s = lsum;
#pragma unroll
            for (int off = 1; off < 64; off <<= 1) {
                int t = __shfl_down(s, off);
                if (tid + off < 64) s += t;
            }
            int tail = s - lsum;
            int acc = c_above_s;
            int need = NT - acc;
            int t3 = tail + hv.w;
            int t2 = t3 + hv.z;
            int t1 = t2 + hv.y;
            int t0 = t1 + hv.x;
            if (t0 >= need && t1 < need) { prefix_s |= (unsigned)(4 * tid + 0) << sh; c_above_s = acc + t1; }
            else if (t1 >= need && t2 < need) { prefix_s |= (unsigned)(4 * tid + 1) << sh; c_above_s = acc + t2; }
            else if (t2 >= need && t3 < need) { prefix_s |= (unsigned)(4 * tid + 2) << sh; c_above_s = acc + t3; }
            else if (t3 >= need && tail < need) { prefix_s |= (unsigned)(4 * tid + 3) << sh; c_above_s = acc + tail; }
        }
        __syncthreads();
    }

    unsigned int T = prefix_s;

#pragma unroll
    for (int j = 0; j < 8; j++) {
        if (o[j] > T) {
            int slot = atomicAdd(&nsel_s, 1);
            int myidx = tid * 8 + j;
            topidx[bh * NT + slot] = myidx;
            atomicOr(&bw[myidx >> 5], 1u << (myidx & 31));
        } else if (o[j] == T) {
            int p = atomicAdd(&ntie_s, 1);
            tie_i[p] = tid * 8 + j;
        }
    }
    __syncthreads();
    if (tid == 0) r_s = NT - nsel_s;
    __syncthreads();
    int r = r_s, ntie = ntie_s;

#pragma unroll
    for (int j = 0; j < 8; j++) {
        if (o[j] == T) {
            int myidx = tid * 8 + j;
            int rank = 0;
            for (int p = 0; p < ntie; p++) rank += (tie_i[p] < myidx) ? 1 : 0;
            if (rank < r) {
                int slot = atomicAdd(&nsel_s, 1);
                topidx[bh * NT + slot] = myidx;
                atomicOr(&bw[myidx >> 5], 1u << (myidx & 31));
            }
        }
    }
    __syncthreads();
    if (tid < 64) bitmap[bh * 64 + tid] = bw[tid];
}

// ---------------------------------------------------------------- K3: attention partials + bitmap-fill + fused combine
// R10/11 column-split attn (proven). Fill skips bitmap-selected rows (combine
// alone writes them -> no race). Last attn block per bh (device-scope counter)
// runs the combine+scatter for that bh.
template <int NCH_>
__global__ __launch_bounds__(512) void k_attn_fill(
        const float* __restrict__ q, const float* __restrict__ k,
        const float* __restrict__ v, const int* __restrict__ topidx,
        const float* __restrict__ meanv, const unsigned int* __restrict__ bitmap,
        int* cnt, float* pctx, float* pm, float* pl,
        float* __restrict__ out) {
    constexpr int CS_ = S / NCH_;        // 128 @ NCH16
    constexpr int CPL = CS_ / 128;       // 1 @ NCH16
    int blk = blockIdx.x;
    int bh = blk / NCH_, c = blk % NCH_;
    int b = bh / H, h = bh % H;
    int s0 = c * CS_;
    int tid = threadIdx.x;
    int lane = tid & 63, g = tid >> 6;   // 8 waves

    __shared__ float q_s[NT][D];
    __shared__ float p_s[NT][CS_ + 4];
    __shared__ float m_c[NT];

    for (int i = tid; i < NT * D; i += 512) {
        int n = i >> 6, d = i & 63;
        int lsel = topidx[bh * NT + n];
        q_s[n][d] = q[((size_t)(b * L + lsel) * H + h) * D + d];
    }
    __syncthreads();

    int rg = g & 3, ch = g >> 2;
    int r0 = rg * 10;
    int lc = ch * (CS_ / 2) + lane * CPL;
    const float* kp = k + ((size_t)(b * S + s0 + lc) * H + h) * D;

    float sc[10][CPL];
#pragma unroll
    for (int j = 0; j < 10; j++)
#pragma unroll
        for (int p = 0; p < CPL; p++) sc[j][p] = 0.f;

#pragma unroll
    for (int dc = 0; dc < 64; dc += 16) {
        float4 kf[CPL][4];
#pragma unroll
        for (int p = 0; p < CPL; p++) {
            const float* kc = kp + (size_t)p * H * D + dc;
            kf[p][0] = *(const float4*)(kc);
            kf[p][1] = *(const float4*)(kc + 4);
            kf[p][2] = *(const float4*)(kc + 8);
            kf[p][3] = *(const float4*)(kc + 12);
        }
#pragma unroll
        for (int j = 0; j < 10; j++) {
            const float4* qr = (const float4*)&q_s[r0 + j][dc];
            float4 q0 = qr[0], q1 = qr[1], q2 = qr[2], q3 = qr[3];
#pragma unroll
            for (int p = 0; p < CPL; p++) {
                sc[j][p] += q0.x * kf[p][0].x + q0.y * kf[p][0].y + q0.z * kf[p][0].z + q0.w * kf[p][0].w
                          + q1.x * kf[p][1].x + q1.y * kf[p][1].y + q1.z * kf[p][1].z + q1.w * kf[p][1].w
                          + q2.x * kf[p][2].x + q2.y * kf[p][2].y + q2.z * kf[p][2].z + q2.w * kf[p][2].w
                          + q3.x * kf[p][3].x + q3.y * kf[p][3].y + q3.z * kf[p][3].z + q3.w * kf[p][3].w;
            }
        }
    }
#pragma unroll
    for (int j = 0; j < 10; j++) {
#pragma unroll
        for (int p = 0; p < CPL; p++) sc[j][p] *= SCALE;
        if (CPL == 1) p_s[r0 + j][lc] = sc[j][0];
        else *(float2*)&p_s[r0 + j][lc] = make_float2(sc[j][0], sc[j][1]);
    }
    __syncthreads();

    for (int n = g; n < NT; n += 8) {
        float mx = -INFINITY;
#pragma unroll
        for (int jj = 0; jj < CS_ / 64; jj++) mx = fmaxf(mx, p_s[n][lane + 64 * jj]);
#pragma unroll
        for (int off = 1; off < 64; off <<= 1)
            mx = fmaxf(mx, __shfl_xor(mx, off));
        if (lane == 0) m_c[n] = mx;
    }
    __syncthreads();

#pragma unroll
    for (int j = 0; j < 10; j++) {
        float mm = m_c[r0 + j];
        if (CPL == 1) p_s[r0 + j][lc] = __expf(sc[j][0] - mm);
        else *(float2*)&p_s[r0 + j][lc] =
                 make_float2(__expf(sc[j][0] - mm), __expf(sc[j][1] - mm));
    }
    __syncthreads();

    for (int n = g; n < NT; n += 8) {
        float sum = 0.f;
#pragma unroll
        for (int jj = 0; jj < CS_ / 64; jj++) sum += p_s[n][lane + 64 * jj];
#pragma unroll
        for (int off = 1; off < 64; off <<= 1) sum += __shfl_xor(sum, off);
        if (lane == 0) {
            pm[(bh * NCH_ + c) * NT + n] = m_c[n];
            pl[(bh * NCH_ + c) * NT + n] = sum;
        }
    }

    float acc[5];
#pragma unroll
    for (int r = 0; r < 5; r++) acc[r] = 0.f;
    int rp = g * 5;
    const float* vb = v + ((size_t)(b * S + s0) * H + h) * D + lane;
    for (int t4 = 0; t4 < CS_; t4 += 4) {
        float vd0 = vb[(size_t)(t4 + 0) * H * D];
        float vd1 = vb[(size_t)(t4 + 1) * H * D];
        float vd2 = vb[(size_t)(t4 + 2) * H * D];
        float vd3 = vb[(size_t)(t4 + 3) * H * D];
#pragma unroll
        for (int r = 0; r < 5; r++) {
            float4 p4 = *(const float4*)&p_s[rp + r][t4];
            acc[r] += p4.x * vd0 + p4.y * vd1 + p4.z * vd2 + p4.w * vd3;
        }
    }
#pragma unroll
    for (int r = 0; r < 5; r++)
        pctx[((size_t)(bh * NCH_ + c) * NT + rp + r) * D + lane] = acc[r];

    // ---- mean-fill slice of out, skipping bitmap-selected rows
    constexpr int FPB = 1048576 / (32 * NCH_);       // float4s per block
    const float4* mv4 = (const float4*)meanv;
    float4* out4 = (float4*)out;
    size_t base = (size_t)blk * FPB;
#pragma unroll
    for (int j = 0; j < FPB / 512; j++) {
        size_t i = base + tid + (size_t)j * 512;
        int bb = (int)(i >> 18);
        int col4 = (int)(i & 127);
        int ll = (int)((i >> 7) & 2047);
        int hh = col4 >> 4;
        unsigned int w = bitmap[(bb * 8 + hh) * 64 + (ll >> 5)];
        if (!((w >> (ll & 31)) & 1u))
            out4[i] = mv4[(bb << 7) | col4];
    }

    // ---- last block per bh: combine + scatter
    __threadfence();
    __shared__ int is_last;
    if (tid == 0) {
        int old = __hip_atomic_fetch_add(&cnt[bh], 1, __ATOMIC_ACQ_REL,
                                         __HIP_MEMORY_SCOPE_AGENT);
        is_last = (old == NCH_ - 1);
    }
    __syncthreads();
    if (!is_last) return;
    __threadfence();

    for (int i = tid; i < NT * D; i += 512) {
        int n = i >> 6, d = i & 63;
        float mg = -INFINITY;
#pragma unroll
        for (int cc = 0; cc < NCH_; cc++) mg = fmaxf(mg, pm[(bh * NCH_ + cc) * NT + n]);
        float lsum = 0.f, ctx = 0.f;
#pragma unroll
        for (int cc = 0; cc < NCH_; cc++) {
            float w = __expf(pm[(bh * NCH_ + cc) * NT + n] - mg);
            lsum += pl[(bh * NCH_ + cc) * NT + n] * w;
            ctx  += pctx[((size_t)(bh * NCH_ + cc) * NT + n) * D + d] * w;
        }
        int lsel = topidx[bh * NT + n];
        out[((size_t)(b * L + lsel) * H + h) * D + d] = ctx / lsum;
    }
}

// ---------------------------------------------------------------- launch
extern "C" void kernel_launch(void* const* d_in, const int* in_sizes, int n_in,
                              void* d_out, int out_size, void* d_ws, size_t ws_size,
                              hipStream_t stream) {
    const float* q   = (const float*)d_in[0];
    const float* k   = (const float*)d_in[1];
    const float* v   = (const float*)d_in[2];
    const int*   idx = (const int*)d_in[3];
    float* out = (float*)d_out;

    float* ws = (float*)d_ws;
    float*        M      = ws;                              // 65536
    int*          topidx = (int*)(ws + 65536);              // 1280
    float*        meanv  = ws + 65536 + 1280;               // 2048
    float*        part   = meanv + 2048;                    // 65536
    unsigned int* bitmap = (unsigned int*)(part + 65536);   // 2048
    int*          cnt    = (int*)(bitmap + 2048);           // 32
    float*        pm     = (float*)(cnt + 32);

    hipMemsetAsync(cnt, 0, 32 * sizeof(int), stream);
    k_M_meanvpart<<<4096 + 128, 256, 0, stream>>>(q, k, v, idx, M, part);
    k_topk_meanv<<<36, 256, 0, stream>>>(M, topidx, part, meanv, bitmap);

    constexpr size_t base_floats = 65536 + 1280 + 2048 + 65536 + 2048 + 32;
    constexpr size_t need16 = (base_floats + 2ull * (32 * 16 * 40) + 32ull * 16 * 40 * 64) * 4;
    if (ws_size >= need16) {
        constexpr int NCH_ = 16;
        float* pl   = pm + 32 * NCH_ * NT;
        float* pctx = pl + 32 * NCH_ * NT;
        k_attn_fill<NCH_><<<B * H * NCH_, 512, 0, stream>>>(q, k, v, topidx, meanv, bitmap,
                                                            cnt, pctx, pm, pl, out);
    } else {
        constexpr int NCH_ = 8;
        float* pl   = pm + 32 * NCH_ * NT;
        float* pctx = pl + 32 * NCH_ * NT;
        k_attn_fill<NCH_><<<B * H * NCH_, 512, 0, stream>>>(q, k, v, topidx, meanv, bitmap,
                                                            cnt, pctx, pm, pl, out);
    }
}

// Round 14
// 162.250 us; speedup vs baseline: 1.7525x; 1.7525x over previous
//
#include <hip/hip_runtime.h>
#include <math.h>

constexpr int B = 4, L = 2048, S = 2048, H = 8, D = 64;
constexpr int U  = 40;
constexpr int NT = 40;
constexpr float SCALE = 0.125f;

// ---------------------------------------------------------------- K1: M scores + v-mean partials
// M part: 2 waves per l (u split 20/20), lane = h*8+dg; LDS combine.
// No readfirstlane tricks (R12 scratch lesson), no fences (R13 lesson).
__global__ void k_M_meanvpart(const float* __restrict__ q, const float* __restrict__ k,
                              const float* __restrict__ v, const int* __restrict__ idx,
                              float* __restrict__ M, float* __restrict__ part) {
    int tid = threadIdx.x;
    if (blockIdx.x < 4096) {
        int wid = tid >> 6, lane = tid & 63;
        int b = blockIdx.x & 3;
        int lp = wid >> 1, uh = wid & 1;          // local l, u-half
        int l = (blockIdx.x >> 2) * 2 + lp;
        int h = lane >> 3, dg = lane & 7;

        const float4* qr = (const float4*)(q + ((size_t)(b * L + l) * H + h) * D + dg * 8);
        float4 q0 = qr[0], q1 = qr[1];

        const int* irow = idx + l * U + uh * 20;
        const float* kb = k + (size_t)b * S * H * D + (size_t)h * D + dg * 8;
        float vmax = -INFINITY, vsum = 0.f;
#pragma unroll 4
        for (int u = 0; u < 20; u++) {
            int s = irow[u];
            const float4* kr = (const float4*)(kb + (size_t)s * H * D);
            float4 k0 = kr[0], k1 = kr[1];
            float acc = q0.x * k0.x + q0.y * k0.y + q0.z * k0.z + q0.w * k0.w
                      + q1.x * k1.x + q1.y * k1.y + q1.z * k1.z + q1.w * k1.w;
            acc += __shfl_xor(acc, 1);
            acc += __shfl_xor(acc, 2);
            acc += __shfl_xor(acc, 4);
            vmax = fmaxf(vmax, acc);
            vsum += acc;
        }
        __shared__ float2 comb[4][8];
        if (dg == 0) comb[wid][h] = make_float2(vmax, vsum);
        __syncthreads();
        if (tid < 16) {
            int lp2 = tid >> 3, h2 = tid & 7;
            float2 c0 = comb[lp2 * 2][h2], c1 = comb[lp2 * 2 + 1][h2];
            float mx = fmaxf(c0.x, c1.x);
            float sm = c0.y + c1.y;
            int l2 = (blockIdx.x >> 2) * 2 + lp2;
            M[(size_t)(b * H + h2) * L + l2] = mx - sm / (float)S;
        }
    } else {
        int blk = blockIdx.x - 4096;         // 0..127 = b*32 + c
        int b = blk >> 5, c = blk & 31;
        const float* p = v + ((size_t)(b * S + c * 64)) * 512;
        float a0 = 0.f, a1 = 0.f;
#pragma unroll
        for (int s = 0; s < 64; s++) {
            a0 += p[(size_t)s * 512 + tid];
            a1 += p[(size_t)s * 512 + tid + 256];
        }
        part[(size_t)blk * 512 + tid]       = a0;
        part[(size_t)blk * 512 + tid + 256] = a1;
    }
}

// ---------------------------------------------------------------- K2: top-40 radix select + v-mean final
__device__ inline unsigned int fkey(float f) {
    unsigned int u = __float_as_uint(f);
    return (u & 0x80000000u) ? ~u : (u | 0x80000000u);
}

__global__ void k_topk_meanv(const float* __restrict__ M, int* __restrict__ topidx,
                             const float* __restrict__ part, float* __restrict__ meanv) {
    int tid = threadIdx.x;
    if (blockIdx.x >= 32) {
        int b = blockIdx.x - 32;             // 0..3
        float a0 = 0.f, a1 = 0.f;
#pragma unroll
        for (int c = 0; c < 32; c++) {
            a0 += part[(size_t)(b * 32 + c) * 512 + tid];
            a1 += part[(size_t)(b * 32 + c) * 512 + tid + 256];
        }
        meanv[b * 512 + tid]       = a0 * (1.f / (float)S);
        meanv[b * 512 + tid + 256] = a1 * (1.f / (float)S);
        return;
    }
    int bh = blockIdx.x;
    const float* m = M + (size_t)bh * L;

    __shared__ int hist[256];
    __shared__ unsigned int prefix_s;
    __shared__ int c_above_s, nsel_s, ntie_s, r_s;
    __shared__ int tie_i[L];

    unsigned int o[8];
    const float4* mr = (const float4*)(m + tid * 8);
    float4 a0 = mr[0], a1 = mr[1];
    o[0] = fkey(a0.x); o[1] = fkey(a0.y); o[2] = fkey(a0.z); o[3] = fkey(a0.w);
    o[4] = fkey(a1.x); o[5] = fkey(a1.y); o[6] = fkey(a1.z); o[7] = fkey(a1.w);

    if (tid == 0) { prefix_s = 0u; c_above_s = 0; nsel_s = 0; ntie_s = 0; }

    for (int sh = 24; sh >= 0; sh -= 8) {
        hist[tid] = 0;
        __syncthreads();
        unsigned int pfx = prefix_s;
#pragma unroll
        for (int j = 0; j < 8; j++) {
            bool match = (sh == 24) || ((o[j] >> (sh + 8)) == (pfx >> (sh + 8)));
            if (match) atomicAdd(&hist[(o[j] >> sh) & 0xFF], 1);
        }
        __syncthreads();
        if (tid < 64) {
            int4 hv = *(const int4*)&hist[tid * 4];
            int lsum = hv.x + hv.y + hv.z + hv.w;
            int s = lsum;
#pragma unroll
            for (int off = 1; off < 64; off <<= 1) {
                int t = __shfl_down(s, off);
                if (tid + off < 64) s += t;
            }
            int tail = s - lsum;
            int acc = c_above_s;
            int need = NT - acc;
            int t3 = tail + hv.w;
            int t2 = t3 + hv.z;
            int t1 = t2 + hv.y;
            int t0 = t1 + hv.x;
            if (t0 >= need && t1 < need) { prefix_s |= (unsigned)(4 * tid + 0) << sh; c_above_s = acc + t1; }
            else if (t1 >= need && t2 < need) { prefix_s |= (unsigned)(4 * tid + 1) << sh; c_above_s = acc + t2; }
            else if (t2 >= need && t3 < need) { prefix_s |= (unsigned)(4 * tid + 2) << sh; c_above_s = acc + t3; }
            else if (t3 >= need && tail < need) { prefix_s |= (unsigned)(4 * tid + 3) << sh; c_above_s = acc + tail; }
        }
        __syncthreads();
    }

    unsigned int T = prefix_s;

#pragma unroll
    for (int j = 0; j < 8; j++) {
        if (o[j] > T) {
            int slot = atomicAdd(&nsel_s, 1);
            topidx[bh * NT + slot] = tid * 8 + j;
        } else if (o[j] == T) {
            int p = atomicAdd(&ntie_s, 1);
            tie_i[p] = tid * 8 + j;
        }
    }
    __syncthreads();
    if (tid == 0) r_s = NT - nsel_s;
    __syncthreads();
    int r = r_s, ntie = ntie_s;

#pragma unroll
    for (int j = 0; j < 8; j++) {
        if (o[j] == T) {
            int myidx = tid * 8 + j;
            int rank = 0;
            for (int p = 0; p < ntie; p++) rank += (tie_i[p] < myidx) ? 1 : 0;
            if (rank < r) {
                int slot = atomicAdd(&nsel_s, 1);
                topidx[bh * NT + slot] = myidx;
            }
        }
    }
}

// ---------------------------------------------------------------- K3: attention partials + mean-fill
template <int NCH_>
__global__ __launch_bounds__(512) void k_attn_fill(
        const float* __restrict__ q, const float* __restrict__ k,
        const float* __restrict__ v, const int* __restrict__ topidx,
        const float* __restrict__ meanv,
        float* __restrict__ pctx, float* __restrict__ pm, float* __restrict__ pl,
        float4* __restrict__ out4) {
    constexpr int CS_ = S / NCH_;        // 128 @ NCH16
    constexpr int CPL = CS_ / 128;       // 1 @ NCH16
    int blk = blockIdx.x;
    int bh = blk / NCH_, c = blk % NCH_;
    int b = bh / H, h = bh % H;
    int s0 = c * CS_;
    int tid = threadIdx.x;
    int lane = tid & 63, g = tid >> 6;   // 8 waves

    __shared__ float q_s[NT][D];
    __shared__ float p_s[NT][CS_ + 4];
    __shared__ float m_c[NT];

    for (int i = tid; i < NT * D; i += 512) {
        int n = i >> 6, d = i & 63;
        int lsel = topidx[bh * NT + n];
        q_s[n][d] = q[((size_t)(b * L + lsel) * H + h) * D + d];
    }
    __syncthreads();

    int rg = g & 3, ch = g >> 2;
    int r0 = rg * 10;
    int lc = ch * (CS_ / 2) + lane * CPL;
    const float* kp = k + ((size_t)(b * S + s0 + lc) * H + h) * D;

    float sc[10][CPL];
#pragma unroll
    for (int j = 0; j < 10; j++)
#pragma unroll
        for (int p = 0; p < CPL; p++) sc[j][p] = 0.f;

#pragma unroll
    for (int dc = 0; dc < 64; dc += 16) {
        float4 kf[CPL][4];
#pragma unroll
        for (int p = 0; p < CPL; p++) {
            const float* kc = kp + (size_t)p * H * D + dc;
            kf[p][0] = *(const float4*)(kc);
            kf[p][1] = *(const float4*)(kc + 4);
            kf[p][2] = *(const float4*)(kc + 8);
            kf[p][3] = *(const float4*)(kc + 12);
        }
#pragma unroll
        for (int j = 0; j < 10; j++) {
            const float4* qr = (const float4*)&q_s[r0 + j][dc];
            float4 q0 = qr[0], q1 = qr[1], q2 = qr[2], q3 = qr[3];
#pragma unroll
            for (int p = 0; p < CPL; p++) {
                sc[j][p] += q0.x * kf[p][0].x + q0.y * kf[p][0].y + q0.z * kf[p][0].z + q0.w * kf[p][0].w
                          + q1.x * kf[p][1].x + q1.y * kf[p][1].y + q1.z * kf[p][1].z + q1.w * kf[p][1].w
                          + q2.x * kf[p][2].x + q2.y * kf[p][2].y + q2.z * kf[p][2].z + q2.w * kf[p][2].w
                          + q3.x * kf[p][3].x + q3.y * kf[p][3].y + q3.z * kf[p][3].z + q3.w * kf[p][3].w;
            }
        }
    }
#pragma unroll
    for (int j = 0; j < 10; j++) {
#pragma unroll
        for (int p = 0; p < CPL; p++) sc[j][p] *= SCALE;
        if (CPL == 1) p_s[r0 + j][lc] = sc[j][0];
        else *(float2*)&p_s[r0 + j][lc] = make_float2(sc[j][0], sc[j][1]);
    }
    __syncthreads();

    for (int n = g; n < NT; n += 8) {
        float mx = -INFINITY;
#pragma unroll
        for (int jj = 0; jj < CS_ / 64; jj++) mx = fmaxf(mx, p_s[n][lane + 64 * jj]);
#pragma unroll
        for (int off = 1; off < 64; off <<= 1)
            mx = fmaxf(mx, __shfl_xor(mx, off));
        if (lane == 0) m_c[n] = mx;
    }
    __syncthreads();

#pragma unroll
    for (int j = 0; j < 10; j++) {
        float mm = m_c[r0 + j];
        if (CPL == 1) p_s[r0 + j][lc] = __expf(sc[j][0] - mm);
        else *(float2*)&p_s[r0 + j][lc] =
                 make_float2(__expf(sc[j][0] - mm), __expf(sc[j][1] - mm));
    }
    __syncthreads();

    for (int n = g; n < NT; n += 8) {
        float sum = 0.f;
#pragma unroll
        for (int jj = 0; jj < CS_ / 64; jj++) sum += p_s[n][lane + 64 * jj];
#pragma unroll
        for (int off = 1; off < 64; off <<= 1) sum += __shfl_xor(sum, off);
        if (lane == 0) {
            pm[(bh * NCH_ + c) * NT + n] = m_c[n];
            pl[(bh * NCH_ + c) * NT + n] = sum;
        }
    }

    float acc[5];
#pragma unroll
    for (int r = 0; r < 5; r++) acc[r] = 0.f;
    int rp = g * 5;
    const float* vb = v + ((size_t)(b * S + s0) * H + h) * D + lane;
    for (int t4 = 0; t4 < CS_; t4 += 4) {
        float vd0 = vb[(size_t)(t4 + 0) * H * D];
        float vd1 = vb[(size_t)(t4 + 1) * H * D];
        float vd2 = vb[(size_t)(t4 + 2) * H * D];
        float vd3 = vb[(size_t)(t4 + 3) * H * D];
#pragma unroll
        for (int r = 0; r < 5; r++) {
            float4 p4 = *(const float4*)&p_s[rp + r][t4];
            acc[r] += p4.x * vd0 + p4.y * vd1 + p4.z * vd2 + p4.w * vd3;
        }
    }
#pragma unroll
    for (int r = 0; r < 5; r++)
        pctx[((size_t)(bh * NCH_ + c) * NT + rp + r) * D + lane] = acc[r];

    // ---- mean-fill slice of out (independent of attn phases above)
    constexpr int FPB = 1048576 / (32 * NCH_);       // float4s per block (2048 @ NCH16)
    const float4* mv4 = (const float4*)meanv;
    size_t base = (size_t)blk * FPB;
#pragma unroll
    for (int j = 0; j < FPB / 512; j++) {
        size_t i = base + tid + (size_t)j * 512;
        int bb = (int)(i >> 18);
        int col4 = (int)(i & 127);
        out4[i] = mv4[(bb << 7) | col4];
    }
}

// ---------------------------------------------------------------- K4: combine + scatter
template <int NCH_>
__global__ void k_combine(const int* __restrict__ topidx, const float* __restrict__ pctx,
                          const float* __restrict__ pm, const float* __restrict__ pl,
                          float* __restrict__ out) {
    int bh = blockIdx.x; int b = bh / H, h = bh % H;
    int tid = threadIdx.x;
    for (int i = tid; i < NT * D; i += 256) {
        int n = i / D, d = i % D;
        float mg = -INFINITY;
#pragma unroll
        for (int c = 0; c < NCH_; c++) mg = fmaxf(mg, pm[(bh * NCH_ + c) * NT + n]);
        float lsum = 0.f, ctx = 0.f;
#pragma unroll
        for (int c = 0; c < NCH_; c++) {
            float w = __expf(pm[(bh * NCH_ + c) * NT + n] - mg);
            lsum += pl[(bh * NCH_ + c) * NT + n] * w;
            ctx  += pctx[((size_t)(bh * NCH_ + c) * NT + n) * D + d] * w;
        }
        int lsel = topidx[bh * NT + n];
        out[((size_t)(b * L + lsel) * H + h) * D + d] = ctx / lsum;
    }
}

// ---------------------------------------------------------------- launch
extern "C" void kernel_launch(void* const* d_in, const int* in_sizes, int n_in,
                              void* d_out, int out_size, void* d_ws, size_t ws_size,
                              hipStream_t stream) {
    const float* q   = (const float*)d_in[0];
    const float* k   = (const float*)d_in[1];
    const float* v   = (const float*)d_in[2];
    const int*   idx = (const int*)d_in[3];
    float* out = (float*)d_out;

    float* ws = (float*)d_ws;
    float* M      = ws;                         // 65536 floats
    int*   topidx = (int*)(ws + 65536);         // 1280 ints
    float* meanv  = ws + 65536 + 1280;          // 2048
    float* part   = meanv + 2048;               // 128*512 = 65536
    float* pm     = part + 65536;               // B*H*NCH*NT

    k_M_meanvpart<<<4096 + 128, 256, 0, stream>>>(q, k, v, idx, M, part);
    k_topk_meanv<<<36, 256, 0, stream>>>(M, topidx, part, meanv);

    constexpr size_t base_floats = 65536 + 1280 + 2048 + 65536;
    constexpr size_t need16 = (base_floats + 2ull * (32 * 16 * 40) + 32ull * 16 * 40 * 64) * 4;
    if (ws_size >= need16) {
        constexpr int NCH_ = 16;
        float* pl   = pm + 32 * NCH_ * NT;
        float* pctx = pl + 32 * NCH_ * NT;
        k_attn_fill<NCH_><<<B * H * NCH_, 512, 0, stream>>>(q, k, v, topidx, meanv,
                                                            pctx, pm, pl, (float4*)out);
        k_combine<NCH_><<<B * H, 256, 0, stream>>>(topidx, pctx, pm, pl, out);
    } else {
        constexpr int NCH_ = 8;
        float* pl   = pm + 32 * NCH_ * NT;
        float* pctx = pl + 32 * NCH_ * NT;
        k_attn_fill<NCH_><<<B * H * NCH_, 512, 0, stream>>>(q, k, v, topidx, meanv,
                                                            pctx, pm, pl, (float4*)out);
        k_combine<NCH_><<<B * H, 256, 0, stream>>>(topidx, pctx, pm, pl, out);
    }
}